// Round 1
// baseline (571.319 us; speedup 1.0000x reference)
//
#include <hip/hip_runtime.h>
#include <hip/hip_fp16.h>
#include <math.h>

#define T_DIM 4096
#define MOL_N 2048
#define DESC_N 6
#define NSOL_N 5
#define H_DIM 2048
#define DBLK 2054
#define D_IN_N 12325

typedef _Float16 f16x8 __attribute__((ext_vector_type(8)));
typedef float f32x4 __attribute__((ext_vector_type(4)));

__device__ __forceinline__ float gelu_f(float x) {
    return 0.5f * x * (1.0f + erff(x * 0.7071067811865476f));
}

// ---- Kernel 1: fold layer-0 weights against the static input structure ----
// fold layout (floats, per trunk): [0,H)=c0(+bias), [(1+s)H,..)=u_s (s<5),
// [(6+j)H,..)=wd_j (j<6), [12H,13H)=wprev
__global__ __launch_bounds__(256) void fold_kernel(
    const float* __restrict__ W0f, const float* __restrict__ W0b,
    const float* __restrict__ b0f, const float* __restrict__ b0b,
    const float* __restrict__ mol, const float* __restrict__ sv,
    float* __restrict__ fold_f, float* __restrict__ fold_b)
{
    const int h = blockIdx.x;
    const int z = blockIdx.y;
    const float* __restrict__ W0 = z ? W0b : W0f;
    const float* __restrict__ b0 = z ? b0b : b0f;
    float* __restrict__ fold = z ? fold_b : fold_f;
    const float* __restrict__ row = W0 + (size_t)h * D_IN_N;
    const int tid = threadIdx.x;

    float acc[6] = {0.f, 0.f, 0.f, 0.f, 0.f, 0.f};
    for (int c = tid; c < MOL_N; c += 256) {
        float m = mol[c];
        acc[0] += row[c] * m;
        #pragma unroll
        for (int s = 0; s < NSOL_N; ++s)
            acc[1 + s] += row[DBLK * (s + 1) + c] * sv[s * MOL_N + c];
    }
    #pragma unroll
    for (int i = 0; i < 6; ++i) {
        float v = acc[i];
        #pragma unroll
        for (int off = 32; off >= 1; off >>= 1)
            v += __shfl_xor(v, off, 64);
        acc[i] = v;
    }
    __shared__ float red[4][6];
    const int lane = tid & 63, wave = tid >> 6;
    if (lane == 0) {
        #pragma unroll
        for (int i = 0; i < 6; ++i) red[wave][i] = acc[i];
    }
    __syncthreads();
    if (tid < 6) {
        float s = red[0][tid] + red[1][tid] + red[2][tid] + red[3][tid];
        if (tid == 0) fold[h] = s + b0[h];
        else fold[(size_t)tid * H_DIM + h] = s;   // u_s at (1+s)H with s=tid-1
    }
    if (tid >= 64 && tid < 70) {
        int j = tid - 64;
        float w = row[MOL_N + j];
        #pragma unroll
        for (int s = 0; s < NSOL_N; ++s) w += row[DBLK * (s + 1) + MOL_N + j];
        fold[(size_t)(6 + j) * H_DIM + h] = w;
    }
    if (tid == 70) fold[(size_t)12 * H_DIM + h] = row[D_IN_N - 1];
}

// ---- Kernel 2: convert W1/W2 (both trunks) fp32 -> fp16 ----
__global__ __launch_bounds__(256) void conv_kernel(
    const float* __restrict__ W1f, const float* __restrict__ W2f,
    const float* __restrict__ W1b, const float* __restrict__ W2b,
    _Float16* __restrict__ dstbase)
{
    const int z = blockIdx.y;
    const float* __restrict__ src = (z == 0) ? W1f : (z == 1) ? W2f : (z == 2) ? W1b : W2b;
    _Float16* __restrict__ dst = dstbase + (size_t)z * H_DIM * H_DIM;
    const int idx = blockIdx.x * 256 + threadIdx.x;
    float4 v = ((const float4*)src)[idx];
    struct h4 { _Float16 a, b, c, d; };
    h4 o;
    o.a = (_Float16)v.x; o.b = (_Float16)v.y; o.c = (_Float16)v.z; o.d = (_Float16)v.w;
    ((h4*)dst)[idx] = o;
}

// ---- Kernel 3: h0 = gelu(folded layer-0), store fp16 ----
__global__ __launch_bounds__(256) void h0_kernel(
    const float* __restrict__ fold_f, const float* __restrict__ fold_b,
    const float* __restrict__ desc, const float* __restrict__ sol,
    const float* __restrict__ rf,
    _Float16* __restrict__ h0f, _Float16* __restrict__ h0b)
{
    const int z = blockIdx.z;
    const float* __restrict__ fold = z ? fold_b : fold_f;
    _Float16* __restrict__ h0 = z ? h0b : h0f;
    const int h = blockIdx.x * 256 + threadIdx.x;
    const int tbase = blockIdx.y * 64;

    const float c0 = fold[h];
    float u[NSOL_N], wd[DESC_N];
    #pragma unroll
    for (int s = 0; s < NSOL_N; ++s) u[s] = fold[(size_t)(1 + s) * H_DIM + h];
    #pragma unroll
    for (int j = 0; j < DESC_N; ++j) wd[j] = fold[(size_t)(6 + j) * H_DIM + h];
    const float wp = fold[(size_t)12 * H_DIM + h];

    for (int i = 0; i < 64; ++i) {
        const int t = tbase + i;
        float pv;
        if (z == 0) pv = (t == 0) ? 0.5f : rf[t - 1];
        else        pv = (t == T_DIM - 1) ? 0.5f : rf[t + 1];
        float pre = c0 + wp * pv;
        #pragma unroll
        for (int s = 0; s < NSOL_N; ++s) pre += u[s] * sol[t * NSOL_N + s];
        #pragma unroll
        for (int j = 0; j < DESC_N; ++j) pre += wd[j] * desc[t * DESC_N + j];
        h0[(size_t)t * H_DIM + h] = (_Float16)gelu_f(pre);
    }
}

// ---- Kernel 4: batched GEMM  C[m,n] = gelu(sum_k A[m,k]*W[n,k] + bias[n]) ----
// m97 structure: 128x128 tile, BK=32, global_load_lds width16, mfma 16x16x32 f16
__global__ __launch_bounds__(256) void gemm_kernel(
    const _Float16* __restrict__ Af, const _Float16* __restrict__ Ab,
    const _Float16* __restrict__ Wfp, const _Float16* __restrict__ Wbp,
    const float* __restrict__ bfp, const float* __restrict__ bbp,
    _Float16* __restrict__ Cf, _Float16* __restrict__ Cb)
{
    constexpr int K = H_DIM;
    constexpr int N = H_DIM;
    const int z = blockIdx.z;
    const _Float16* __restrict__ A = z ? Ab : Af;
    const _Float16* __restrict__ W = z ? Wbp : Wfp;
    const float* __restrict__ bias = z ? bbp : bfp;
    _Float16* __restrict__ C = z ? Cb : Cf;

    __shared__ _Float16 sA[128 * 32];
    __shared__ _Float16 sB[128 * 32];

    const int tid = threadIdx.x;
    const int m0 = blockIdx.y * 128;
    const int n0 = blockIdx.x * 128;
    const int wave = tid >> 6;
    const int lane = tid & 63;
    const int quad = lane >> 4;

    // staging: chunk c (16B) covers tile row c/4, k-bytes (c%4)*16
    const int c0 = tid;
    const int c1 = tid + 256;
    const _Float16* gA0 = A + (size_t)(m0 + (c0 >> 2)) * K + (c0 & 3) * 8;
    const _Float16* gA1 = A + (size_t)(m0 + (c1 >> 2)) * K + (c1 & 3) * 8;
    const _Float16* gB0 = W + (size_t)(n0 + (c0 >> 2)) * K + (c0 & 3) * 8;
    const _Float16* gB1 = W + (size_t)(n0 + (c1 >> 2)) * K + (c1 & 3) * 8;

    char* sAc = (char*)sA;
    char* sBc = (char*)sB;
    void* ldsA0 = sAc + wave * 1024;
    void* ldsA1 = sAc + 4096 + wave * 1024;
    void* ldsB0 = sBc + wave * 1024;
    void* ldsB1 = sBc + 4096 + wave * 1024;

    f32x4 acc[4][4];
    #pragma unroll
    for (int i = 0; i < 4; ++i)
        #pragma unroll
        for (int j = 0; j < 4; ++j)
            acc[i][j] = (f32x4){0.f, 0.f, 0.f, 0.f};

    const int rA = (wave & 1) * 64 + (lane & 15);
    const int rB = (wave >> 1) * 64 + (lane & 15);

    for (int k0 = 0; k0 < K; k0 += 32) {
        __builtin_amdgcn_global_load_lds((const __attribute__((address_space(1))) void*)(gA0 + k0),
                                         (__attribute__((address_space(3))) void*)ldsA0, 16, 0, 0);
        __builtin_amdgcn_global_load_lds((const __attribute__((address_space(1))) void*)(gA1 + k0),
                                         (__attribute__((address_space(3))) void*)ldsA1, 16, 0, 0);
        __builtin_amdgcn_global_load_lds((const __attribute__((address_space(1))) void*)(gB0 + k0),
                                         (__attribute__((address_space(3))) void*)ldsB0, 16, 0, 0);
        __builtin_amdgcn_global_load_lds((const __attribute__((address_space(1))) void*)(gB1 + k0),
                                         (__attribute__((address_space(3))) void*)ldsB1, 16, 0, 0);
        __syncthreads();
        f16x8 aF[4], bF[4];
        #pragma unroll
        for (int mi = 0; mi < 4; ++mi)
            aF[mi] = *(const f16x8*)(sAc + (((rA + mi * 16) * 32 + quad * 8) * 2));
        #pragma unroll
        for (int ni = 0; ni < 4; ++ni)
            bF[ni] = *(const f16x8*)(sBc + (((rB + ni * 16) * 32 + quad * 8) * 2));
        #pragma unroll
        for (int mi = 0; mi < 4; ++mi)
            #pragma unroll
            for (int ni = 0; ni < 4; ++ni)
                acc[mi][ni] = __builtin_amdgcn_mfma_f32_16x16x32_f16(aF[mi], bF[ni], acc[mi][ni], 0, 0, 0);
        __syncthreads();
    }

    // epilogue: C/D layout col=lane&15, row=quad*4+reg
    const int colC = lane & 15;
    #pragma unroll
    for (int ni = 0; ni < 4; ++ni) {
        const int n = n0 + (wave >> 1) * 64 + ni * 16 + colC;
        const float bv = bias[n];
        #pragma unroll
        for (int mi = 0; mi < 4; ++mi) {
            const int mb = m0 + (wave & 1) * 64 + mi * 16 + quad * 4;
            #pragma unroll
            for (int r = 0; r < 4; ++r) {
                float v = acc[mi][ni][r] + bv;
                C[(size_t)(mb + r) * N + n] = (_Float16)gelu_f(v);
            }
        }
    }
}

// ---- Kernel 5: output head, clip ----
__global__ __launch_bounds__(256) void out_kernel(
    const _Float16* __restrict__ h2f, const _Float16* __restrict__ h2b,
    const float* __restrict__ Wof, const float* __restrict__ Wob,
    const float* __restrict__ bof, const float* __restrict__ bob,
    float* __restrict__ out)
{
    const int t = blockIdx.x;
    const int z = blockIdx.y;
    const _Float16* __restrict__ h2 = z ? h2b : h2f;
    const float* __restrict__ Wo = z ? Wob : Wof;
    const float bo = z ? bob[0] : bof[0];
    const int tid = threadIdx.x;
    const int c = tid * 8;
    const f16x8 hv = *(const f16x8*)(h2 + (size_t)t * H_DIM + c);
    float acc = 0.f;
    #pragma unroll
    for (int j = 0; j < 8; ++j)
        acc += (float)hv[j] * Wo[c + j];
    #pragma unroll
    for (int off = 32; off >= 1; off >>= 1)
        acc += __shfl_xor(acc, off, 64);
    __shared__ float red[4];
    const int lane = tid & 63, wave = tid >> 6;
    if (lane == 0) red[wave] = acc;
    __syncthreads();
    if (tid == 0) {
        float v = red[0] + red[1] + red[2] + red[3] + bo;
        v = fminf(fmaxf(v, 1e-4f), 1.0f - 1e-4f);
        out[(size_t)z * T_DIM + t] = v;
    }
}

extern "C" void kernel_launch(void* const* d_in, const int* in_sizes, int n_in,
                              void* d_out, int out_size, void* d_ws, size_t ws_size,
                              hipStream_t stream)
{
    (void)in_sizes; (void)n_in; (void)out_size; (void)ws_size;
    const float* mol = (const float*)d_in[0];
    const float* sol = (const float*)d_in[1];
    const float* desc = (const float*)d_in[2];
    const float* rf  = (const float*)d_in[3];
    const float* sv  = (const float*)d_in[4];
    const float* Wf0 = (const float*)d_in[5];
    const float* Wf1 = (const float*)d_in[6];
    const float* Wf2 = (const float*)d_in[7];
    const float* Wof = (const float*)d_in[8];
    const float* Wb0 = (const float*)d_in[9];
    const float* Wb1 = (const float*)d_in[10];
    const float* Wb2 = (const float*)d_in[11];
    const float* Wob = (const float*)d_in[12];
    const float* bf0 = (const float*)d_in[13];
    const float* bf1 = (const float*)d_in[14];
    const float* bf2 = (const float*)d_in[15];
    const float* bof = (const float*)d_in[16];
    const float* bb0 = (const float*)d_in[17];
    const float* bb1 = (const float*)d_in[18];
    const float* bb2 = (const float*)d_in[19];
    const float* bob = (const float*)d_in[20];
    float* out = (float*)d_out;

    char* ws = (char*)d_ws;
    float* fold_f = (float*)(ws + 0);          // 13*2048*4 = 106496 B
    float* fold_b = (float*)(ws + 131072);
    _Float16* Wc = (_Float16*)(ws + 262144);   // 4 x 2048*2048 fp16 = 33554432 B
    const size_t WSZ = (size_t)H_DIM * H_DIM;
    _Float16* W1f_c = Wc;
    _Float16* W2f_c = Wc + WSZ;
    _Float16* W1b_c = Wc + 2 * WSZ;
    _Float16* W2b_c = Wc + 3 * WSZ;
    const size_t HSZ = (size_t)T_DIM * H_DIM;  // 8388608 elems, 16777216 B fp16
    _Float16* h0f = (_Float16*)(ws + 33816576);
    _Float16* h0b = h0f + HSZ;
    _Float16* h1f = (_Float16*)(ws + 33816576 + 2 * 16777216);
    _Float16* h1b = h1f + HSZ;
    _Float16* h2f = h0f;  // reuse: h0 dead after layer 1
    _Float16* h2b = h0b;
    // total ws use: 33816576 + 4*16777216 = 100,925,440 B

    fold_kernel<<<dim3(H_DIM, 2), 256, 0, stream>>>(Wf0, Wb0, bf0, bb0, mol, sv, fold_f, fold_b);
    conv_kernel<<<dim3(H_DIM * H_DIM / 1024, 4), 256, 0, stream>>>(Wf1, Wf2, Wb1, Wb2, Wc);
    h0_kernel<<<dim3(8, 64, 2), 256, 0, stream>>>(fold_f, fold_b, desc, sol, rf, h0f, h0b);
    gemm_kernel<<<dim3(16, 32, 2), 256, 0, stream>>>(h0f, h0b, W1f_c, W1b_c, bf1, bb1, h1f, h1b);
    gemm_kernel<<<dim3(16, 32, 2), 256, 0, stream>>>(h1f, h1b, W2f_c, W2b_c, bf2, bb2, h2f, h2b);
    out_kernel<<<dim3(T_DIM, 2), 256, 0, stream>>>(h2f, h2b, Wof, Wob, bof, bob, out);
}

// Round 2
// 521.214 us; speedup vs baseline: 1.0961x; 1.0961x over previous
//
#include <hip/hip_runtime.h>
#include <hip/hip_fp16.h>
#include <math.h>

#define T_DIM 4096
#define MOL_N 2048
#define DESC_N 6
#define NSOL_N 5
#define H_DIM 2048
#define DBLK 2054
#define D_IN_N 12325

typedef _Float16 f16x8 __attribute__((ext_vector_type(8)));
typedef float f32x4 __attribute__((ext_vector_type(4)));

__device__ __forceinline__ float gelu_f(float x) {
    return 0.5f * x * (1.0f + erff(x * 0.7071067811865476f));
}

// ---- Kernel 1: fold layer-0 weights against the static input structure ----
// fold layout (floats, per trunk): [0,H)=c0(+bias), [(1+s)H,..)=u_s (s<5),
// [(6+j)H,..)=wd_j (j<6), [12H,13H)=wprev
__global__ __launch_bounds__(256) void fold_kernel(
    const float* __restrict__ W0f, const float* __restrict__ W0b,
    const float* __restrict__ b0f, const float* __restrict__ b0b,
    const float* __restrict__ mol, const float* __restrict__ sv,
    float* __restrict__ fold_f, float* __restrict__ fold_b)
{
    const int h = blockIdx.x;
    const int z = blockIdx.y;
    const float* __restrict__ W0 = z ? W0b : W0f;
    const float* __restrict__ b0 = z ? b0b : b0f;
    float* __restrict__ fold = z ? fold_b : fold_f;
    const float* __restrict__ row = W0 + (size_t)h * D_IN_N;
    const int tid = threadIdx.x;

    float acc[6] = {0.f, 0.f, 0.f, 0.f, 0.f, 0.f};
    for (int c = tid; c < MOL_N; c += 256) {
        float m = mol[c];
        acc[0] += row[c] * m;
        #pragma unroll
        for (int s = 0; s < NSOL_N; ++s)
            acc[1 + s] += row[DBLK * (s + 1) + c] * sv[s * MOL_N + c];
    }
    #pragma unroll
    for (int i = 0; i < 6; ++i) {
        float v = acc[i];
        #pragma unroll
        for (int off = 32; off >= 1; off >>= 1)
            v += __shfl_xor(v, off, 64);
        acc[i] = v;
    }
    __shared__ float red[4][6];
    const int lane = tid & 63, wave = tid >> 6;
    if (lane == 0) {
        #pragma unroll
        for (int i = 0; i < 6; ++i) red[wave][i] = acc[i];
    }
    __syncthreads();
    if (tid < 6) {
        float s = red[0][tid] + red[1][tid] + red[2][tid] + red[3][tid];
        if (tid == 0) fold[h] = s + b0[h];
        else fold[(size_t)tid * H_DIM + h] = s;   // u_s at (1+s)H with s=tid-1
    }
    if (tid >= 64 && tid < 70) {
        int j = tid - 64;
        float w = row[MOL_N + j];
        #pragma unroll
        for (int s = 0; s < NSOL_N; ++s) w += row[DBLK * (s + 1) + MOL_N + j];
        fold[(size_t)(6 + j) * H_DIM + h] = w;
    }
    if (tid == 70) fold[(size_t)12 * H_DIM + h] = row[D_IN_N - 1];
}

// ---- Kernel 2: convert W1/W2 (both trunks) fp32 -> fp16 ----
__global__ __launch_bounds__(256) void conv_kernel(
    const float* __restrict__ W1f, const float* __restrict__ W2f,
    const float* __restrict__ W1b, const float* __restrict__ W2b,
    _Float16* __restrict__ dstbase)
{
    const int z = blockIdx.y;
    const float* __restrict__ src = (z == 0) ? W1f : (z == 1) ? W2f : (z == 2) ? W1b : W2b;
    _Float16* __restrict__ dst = dstbase + (size_t)z * H_DIM * H_DIM;
    const int idx = blockIdx.x * 256 + threadIdx.x;
    float4 v = ((const float4*)src)[idx];
    struct h4 { _Float16 a, b, c, d; };
    h4 o;
    o.a = (_Float16)v.x; o.b = (_Float16)v.y; o.c = (_Float16)v.z; o.d = (_Float16)v.w;
    ((h4*)dst)[idx] = o;
}

// ---- Kernel 3: h0 = gelu(folded layer-0), store fp16 ----
__global__ __launch_bounds__(256) void h0_kernel(
    const float* __restrict__ fold_f, const float* __restrict__ fold_b,
    const float* __restrict__ desc, const float* __restrict__ sol,
    const float* __restrict__ rf,
    _Float16* __restrict__ h0f, _Float16* __restrict__ h0b)
{
    const int z = blockIdx.z;
    const float* __restrict__ fold = z ? fold_b : fold_f;
    _Float16* __restrict__ h0 = z ? h0b : h0f;
    const int h = blockIdx.x * 256 + threadIdx.x;
    const int tbase = blockIdx.y * 64;

    const float c0 = fold[h];
    float u[NSOL_N], wd[DESC_N];
    #pragma unroll
    for (int s = 0; s < NSOL_N; ++s) u[s] = fold[(size_t)(1 + s) * H_DIM + h];
    #pragma unroll
    for (int j = 0; j < DESC_N; ++j) wd[j] = fold[(size_t)(6 + j) * H_DIM + h];
    const float wp = fold[(size_t)12 * H_DIM + h];

    for (int i = 0; i < 64; ++i) {
        const int t = tbase + i;
        float pv;
        if (z == 0) pv = (t == 0) ? 0.5f : rf[t - 1];
        else        pv = (t == T_DIM - 1) ? 0.5f : rf[t + 1];
        float pre = c0 + wp * pv;
        #pragma unroll
        for (int s = 0; s < NSOL_N; ++s) pre += u[s] * sol[t * NSOL_N + s];
        #pragma unroll
        for (int j = 0; j < DESC_N; ++j) pre += wd[j] * desc[t * DESC_N + j];
        h0[(size_t)t * H_DIM + h] = (_Float16)gelu_f(pre);
    }
}

// ---- Kernel 4: batched GEMM  C[m,n] = gelu(sum_k A[m,k]*W[n,k] + bias[n]) ----
// 128x128 tile, BK=64 (32 barrier drains instead of 64), global_load_lds w16,
// 3-bit XOR k-chunk swizzle: chunk (r,c) lives at LDS r*128 + (c^(r&7))*16 so
// each ds_read_b128 maps 2 lanes per 4-bank group per quad -> conflict-free.
__global__ __launch_bounds__(256) void gemm_kernel(
    const _Float16* __restrict__ Af, const _Float16* __restrict__ Ab,
    const _Float16* __restrict__ Wfp, const _Float16* __restrict__ Wbp,
    const float* __restrict__ bfp, const float* __restrict__ bbp,
    _Float16* __restrict__ Cf, _Float16* __restrict__ Cb)
{
    constexpr int K = H_DIM;
    constexpr int N = H_DIM;
    const int z = blockIdx.z;
    const _Float16* __restrict__ A = z ? Ab : Af;
    const _Float16* __restrict__ W = z ? Wbp : Wfp;
    const float* __restrict__ bias = z ? bbp : bfp;
    _Float16* __restrict__ C = z ? Cb : Cf;

    __shared__ _Float16 sA[128 * 64];   // 16 KB
    __shared__ _Float16 sB[128 * 64];   // 16 KB

    const int tid = threadIdx.x;
    const int m0 = blockIdx.y * 128;
    const int n0 = blockIdx.x * 128;
    const int wave = tid >> 6;
    const int lane = tid & 63;
    const int quad = lane >> 4;

    char* sAc = (char*)sA;
    char* sBc = (char*)sB;

    // staging: 1024 16B-chunks per tile; thread handles j = ld*256 + tid.
    // LDS chunk j holds global chunk (r = j>>3, c = (j&7) ^ (r&7)).
    const _Float16* gA[4];
    const _Float16* gB[4];
    #pragma unroll
    for (int ld = 0; ld < 4; ++ld) {
        const int j = ld * 256 + tid;
        const int r = j >> 3;
        const int c = (j & 7) ^ (r & 7);
        gA[ld] = A + (size_t)(m0 + r) * K + c * 8;
        gB[ld] = W + (size_t)(n0 + r) * K + c * 8;
    }

    f32x4 acc[4][4];
    #pragma unroll
    for (int i = 0; i < 4; ++i)
        #pragma unroll
        for (int j = 0; j < 4; ++j)
            acc[i][j] = (f32x4){0.f, 0.f, 0.f, 0.f};

    const int rA = (wave & 1) * 64 + (lane & 15);
    const int rB = (wave >> 1) * 64 + (lane & 15);
    const int xorL = lane & 7;   // (rA&7) == (rB&7) == lane&7

    for (int k0 = 0; k0 < K; k0 += 64) {
        #pragma unroll
        for (int ld = 0; ld < 4; ++ld)
            __builtin_amdgcn_global_load_lds(
                (const __attribute__((address_space(1))) void*)(gA[ld] + k0),
                (__attribute__((address_space(3))) void*)(sAc + ld * 4096 + wave * 1024), 16, 0, 0);
        #pragma unroll
        for (int ld = 0; ld < 4; ++ld)
            __builtin_amdgcn_global_load_lds(
                (const __attribute__((address_space(1))) void*)(gB[ld] + k0),
                (__attribute__((address_space(3))) void*)(sBc + ld * 4096 + wave * 1024), 16, 0, 0);
        __syncthreads();
        #pragma unroll
        for (int kk = 0; kk < 2; ++kk) {
            const int coff = ((kk * 4 + quad) ^ xorL) * 16;
            f16x8 aF[4], bF[4];
            #pragma unroll
            for (int mi = 0; mi < 4; ++mi)
                aF[mi] = *(const f16x8*)(sAc + (rA + mi * 16) * 128 + coff);
            #pragma unroll
            for (int ni = 0; ni < 4; ++ni)
                bF[ni] = *(const f16x8*)(sBc + (rB + ni * 16) * 128 + coff);
            #pragma unroll
            for (int mi = 0; mi < 4; ++mi)
                #pragma unroll
                for (int ni = 0; ni < 4; ++ni)
                    acc[mi][ni] = __builtin_amdgcn_mfma_f32_16x16x32_f16(aF[mi], bF[ni], acc[mi][ni], 0, 0, 0);
        }
        __syncthreads();
    }

    // epilogue: C/D layout col=lane&15, row=quad*4+reg
    const int colC = lane & 15;
    #pragma unroll
    for (int ni = 0; ni < 4; ++ni) {
        const int n = n0 + (wave >> 1) * 64 + ni * 16 + colC;
        const float bv = bias[n];
        #pragma unroll
        for (int mi = 0; mi < 4; ++mi) {
            const int mb = m0 + (wave & 1) * 64 + mi * 16 + quad * 4;
            #pragma unroll
            for (int r = 0; r < 4; ++r) {
                float v = acc[mi][ni][r] + bv;
                C[(size_t)(mb + r) * N + n] = (_Float16)gelu_f(v);
            }
        }
    }
}

// ---- Kernel 5: output head, clip ----
__global__ __launch_bounds__(256) void out_kernel(
    const _Float16* __restrict__ h2f, const _Float16* __restrict__ h2b,
    const float* __restrict__ Wof, const float* __restrict__ Wob,
    const float* __restrict__ bof, const float* __restrict__ bob,
    float* __restrict__ out)
{
    const int t = blockIdx.x;
    const int z = blockIdx.y;
    const _Float16* __restrict__ h2 = z ? h2b : h2f;
    const float* __restrict__ Wo = z ? Wob : Wof;
    const float bo = z ? bob[0] : bof[0];
    const int tid = threadIdx.x;
    const int c = tid * 8;
    const f16x8 hv = *(const f16x8*)(h2 + (size_t)t * H_DIM + c);
    float acc = 0.f;
    #pragma unroll
    for (int j = 0; j < 8; ++j)
        acc += (float)hv[j] * Wo[c + j];
    #pragma unroll
    for (int off = 32; off >= 1; off >>= 1)
        acc += __shfl_xor(acc, off, 64);
    __shared__ float red[4];
    const int lane = tid & 63, wave = tid >> 6;
    if (lane == 0) red[wave] = acc;
    __syncthreads();
    if (tid == 0) {
        float v = red[0] + red[1] + red[2] + red[3] + bo;
        v = fminf(fmaxf(v, 1e-4f), 1.0f - 1e-4f);
        out[(size_t)z * T_DIM + t] = v;
    }
}

extern "C" void kernel_launch(void* const* d_in, const int* in_sizes, int n_in,
                              void* d_out, int out_size, void* d_ws, size_t ws_size,
                              hipStream_t stream)
{
    (void)in_sizes; (void)n_in; (void)out_size; (void)ws_size;
    const float* mol = (const float*)d_in[0];
    const float* sol = (const float*)d_in[1];
    const float* desc = (const float*)d_in[2];
    const float* rf  = (const float*)d_in[3];
    const float* sv  = (const float*)d_in[4];
    const float* Wf0 = (const float*)d_in[5];
    const float* Wf1 = (const float*)d_in[6];
    const float* Wf2 = (const float*)d_in[7];
    const float* Wof = (const float*)d_in[8];
    const float* Wb0 = (const float*)d_in[9];
    const float* Wb1 = (const float*)d_in[10];
    const float* Wb2 = (const float*)d_in[11];
    const float* Wob = (const float*)d_in[12];
    const float* bf0 = (const float*)d_in[13];
    const float* bf1 = (const float*)d_in[14];
    const float* bf2 = (const float*)d_in[15];
    const float* bof = (const float*)d_in[16];
    const float* bb0 = (const float*)d_in[17];
    const float* bb1 = (const float*)d_in[18];
    const float* bb2 = (const float*)d_in[19];
    const float* bob = (const float*)d_in[20];
    float* out = (float*)d_out;

    char* ws = (char*)d_ws;
    float* fold_f = (float*)(ws + 0);          // 13*2048*4 = 106496 B
    float* fold_b = (float*)(ws + 131072);
    _Float16* Wc = (_Float16*)(ws + 262144);   // 4 x 2048*2048 fp16 = 33554432 B
    const size_t WSZ = (size_t)H_DIM * H_DIM;
    _Float16* W1f_c = Wc;
    _Float16* W2f_c = Wc + WSZ;
    _Float16* W1b_c = Wc + 2 * WSZ;
    _Float16* W2b_c = Wc + 3 * WSZ;
    const size_t HSZ = (size_t)T_DIM * H_DIM;  // 8388608 elems, 16777216 B fp16
    _Float16* h0f = (_Float16*)(ws + 33816576);
    _Float16* h0b = h0f + HSZ;
    _Float16* h1f = (_Float16*)(ws + 33816576 + 2 * 16777216);
    _Float16* h1b = h1f + HSZ;
    _Float16* h2f = h0f;  // reuse: h0 dead after layer 1
    _Float16* h2b = h0b;
    // total ws use: 33816576 + 4*16777216 = 100,925,440 B

    fold_kernel<<<dim3(H_DIM, 2), 256, 0, stream>>>(Wf0, Wb0, bf0, bb0, mol, sv, fold_f, fold_b);
    conv_kernel<<<dim3(H_DIM * H_DIM / 1024, 4), 256, 0, stream>>>(Wf1, Wf2, Wb1, Wb2, Wc);
    h0_kernel<<<dim3(8, 64, 2), 256, 0, stream>>>(fold_f, fold_b, desc, sol, rf, h0f, h0b);
    gemm_kernel<<<dim3(16, 32, 2), 256, 0, stream>>>(h0f, h0b, W1f_c, W1b_c, bf1, bb1, h1f, h1b);
    gemm_kernel<<<dim3(16, 32, 2), 256, 0, stream>>>(h1f, h1b, W2f_c, W2b_c, bf2, bb2, h2f, h2b);
    out_kernel<<<dim3(T_DIM, 2), 256, 0, stream>>>(h2f, h2b, Wof, Wob, bof, bob, out);
}

// Round 3
// 503.646 us; speedup vs baseline: 1.1344x; 1.0349x over previous
//
#include <hip/hip_runtime.h>
#include <hip/hip_fp16.h>
#include <math.h>

#define T_DIM 4096
#define MOL_N 2048
#define DESC_N 6
#define NSOL_N 5
#define H_DIM 2048
#define DBLK 2054
#define D_IN_N 12325

typedef _Float16 f16x8 __attribute__((ext_vector_type(8)));
typedef float f32x4 __attribute__((ext_vector_type(4)));

// tanh-form GELU as x * sigmoid(1.5957691x + 0.0713548x^3).
// Max abs deviation from exact erf-GELU ~2e-4 (margin is ~1.4e-2). ~12 VALU
// instr vs ~30 for erff.
__device__ __forceinline__ float gelu_f(float x) {
    float v = x * (1.5957691f + 0.0713548f * x * x);
    float e = __expf(-v);
    return x / (1.0f + e);
}

// ---- Kernel 1: fold layer-0 weights against the static input structure ----
// fold layout (floats, per trunk): [0,H)=c0(+bias), [(1+s)H,..)=u_s (s<5),
// [(6+j)H,..)=wd_j (j<6), [12H,13H)=wprev
__global__ __launch_bounds__(256) void fold_kernel(
    const float* __restrict__ W0f, const float* __restrict__ W0b,
    const float* __restrict__ b0f, const float* __restrict__ b0b,
    const float* __restrict__ mol, const float* __restrict__ sv,
    float* __restrict__ fold_f, float* __restrict__ fold_b)
{
    const int h = blockIdx.x;
    const int z = blockIdx.y;
    const float* __restrict__ W0 = z ? W0b : W0f;
    const float* __restrict__ b0 = z ? b0b : b0f;
    float* __restrict__ fold = z ? fold_b : fold_f;
    const float* __restrict__ row = W0 + (size_t)h * D_IN_N;
    const int tid = threadIdx.x;

    float acc[6] = {0.f, 0.f, 0.f, 0.f, 0.f, 0.f};
    for (int c = tid; c < MOL_N; c += 256) {
        float m = mol[c];
        acc[0] += row[c] * m;
        #pragma unroll
        for (int s = 0; s < NSOL_N; ++s)
            acc[1 + s] += row[DBLK * (s + 1) + c] * sv[s * MOL_N + c];
    }
    #pragma unroll
    for (int i = 0; i < 6; ++i) {
        float v = acc[i];
        #pragma unroll
        for (int off = 32; off >= 1; off >>= 1)
            v += __shfl_xor(v, off, 64);
        acc[i] = v;
    }
    __shared__ float red[4][6];
    const int lane = tid & 63, wave = tid >> 6;
    if (lane == 0) {
        #pragma unroll
        for (int i = 0; i < 6; ++i) red[wave][i] = acc[i];
    }
    __syncthreads();
    if (tid < 6) {
        float s = red[0][tid] + red[1][tid] + red[2][tid] + red[3][tid];
        if (tid == 0) fold[h] = s + b0[h];
        else fold[(size_t)tid * H_DIM + h] = s;   // u_s at (1+s)H with s=tid-1
    }
    if (tid >= 64 && tid < 70) {
        int j = tid - 64;
        float w = row[MOL_N + j];
        #pragma unroll
        for (int s = 0; s < NSOL_N; ++s) w += row[DBLK * (s + 1) + MOL_N + j];
        fold[(size_t)(6 + j) * H_DIM + h] = w;
    }
    if (tid == 70) fold[(size_t)12 * H_DIM + h] = row[D_IN_N - 1];
}

// ---- Kernel 2: convert W1/W2 (both trunks) fp32 -> fp16 ----
__global__ __launch_bounds__(256) void conv_kernel(
    const float* __restrict__ W1f, const float* __restrict__ W2f,
    const float* __restrict__ W1b, const float* __restrict__ W2b,
    _Float16* __restrict__ dstbase)
{
    const int z = blockIdx.y;
    const float* __restrict__ src = (z == 0) ? W1f : (z == 1) ? W2f : (z == 2) ? W1b : W2b;
    _Float16* __restrict__ dst = dstbase + (size_t)z * H_DIM * H_DIM;
    const int idx = blockIdx.x * 256 + threadIdx.x;
    float4 v = ((const float4*)src)[idx];
    struct h4 { _Float16 a, b, c, d; };
    h4 o;
    o.a = (_Float16)v.x; o.b = (_Float16)v.y; o.c = (_Float16)v.z; o.d = (_Float16)v.w;
    ((h4*)dst)[idx] = o;
}

// ---- Kernel 3: h0 = gelu(folded layer-0), store fp16 ----
__global__ __launch_bounds__(256) void h0_kernel(
    const float* __restrict__ fold_f, const float* __restrict__ fold_b,
    const float* __restrict__ desc, const float* __restrict__ sol,
    const float* __restrict__ rf,
    _Float16* __restrict__ h0f, _Float16* __restrict__ h0b)
{
    const int z = blockIdx.z;
    const float* __restrict__ fold = z ? fold_b : fold_f;
    _Float16* __restrict__ h0 = z ? h0b : h0f;
    const int h = blockIdx.x * 256 + threadIdx.x;
    const int tbase = blockIdx.y * 64;

    const float c0 = fold[h];
    float u[NSOL_N], wd[DESC_N];
    #pragma unroll
    for (int s = 0; s < NSOL_N; ++s) u[s] = fold[(size_t)(1 + s) * H_DIM + h];
    #pragma unroll
    for (int j = 0; j < DESC_N; ++j) wd[j] = fold[(size_t)(6 + j) * H_DIM + h];
    const float wp = fold[(size_t)12 * H_DIM + h];

    for (int i = 0; i < 64; ++i) {
        const int t = tbase + i;
        float pv;
        if (z == 0) pv = (t == 0) ? 0.5f : rf[t - 1];
        else        pv = (t == T_DIM - 1) ? 0.5f : rf[t + 1];
        float pre = c0 + wp * pv;
        #pragma unroll
        for (int s = 0; s < NSOL_N; ++s) pre += u[s] * sol[t * NSOL_N + s];
        #pragma unroll
        for (int j = 0; j < DESC_N; ++j) pre += wd[j] * desc[t * DESC_N + j];
        h0[(size_t)t * H_DIM + h] = (_Float16)gelu_f(pre);
    }
}

// ---- Kernel 4: batched GEMM  C[m,n] = gelu(sum_k A[m,k]*W[n,k] + bias[n]) ----
// 128x128 tile, BK=64, global_load_lds w16, 3-bit XOR k-chunk swizzle
// (conflict-free, verified 0 SQ_LDS_BANK_CONFLICT in r2).
// XCD-aware tile map: xcd = bid&7 owns one trunk z and an 8-m-tile strip x
// all 16 n-tiles, so each per-XCD L2 holds the k-phase slices (A 128KB +
// W 256KB per BK step) across its 128 co-resident blocks.
__global__ __launch_bounds__(256) void gemm_kernel(
    const _Float16* __restrict__ Af, const _Float16* __restrict__ Ab,
    const _Float16* __restrict__ Wfp, const _Float16* __restrict__ Wbp,
    const float* __restrict__ bfp, const float* __restrict__ bbp,
    _Float16* __restrict__ Cf, _Float16* __restrict__ Cb)
{
    constexpr int K = H_DIM;
    constexpr int N = H_DIM;
    const int bid = blockIdx.x;
    const int xcd = bid & 7;
    const int slot = bid >> 3;
    const int z = xcd & 1;
    const int q = xcd >> 1;                     // 0..3: m-strip within trunk
    const int m0 = (q * 8 + (slot & 7)) * 128;  // 32 m-tiles per trunk
    const int n0 = (slot >> 3) * 128;           // 16 n-tiles

    const _Float16* __restrict__ A = z ? Ab : Af;
    const _Float16* __restrict__ W = z ? Wbp : Wfp;
    const float* __restrict__ bias = z ? bbp : bfp;
    _Float16* __restrict__ C = z ? Cb : Cf;

    __shared__ _Float16 sA[128 * 64];   // 16 KB
    __shared__ _Float16 sB[128 * 64];   // 16 KB

    const int tid = threadIdx.x;
    const int wave = tid >> 6;
    const int lane = tid & 63;
    const int quad = lane >> 4;

    char* sAc = (char*)sA;
    char* sBc = (char*)sB;

    // staging: 1024 16B-chunks per tile; thread handles j = ld*256 + tid.
    // LDS chunk j holds global chunk (r = j>>3, c = (j&7) ^ (r&7)).
    const _Float16* gA[4];
    const _Float16* gB[4];
    #pragma unroll
    for (int ld = 0; ld < 4; ++ld) {
        const int j = ld * 256 + tid;
        const int r = j >> 3;
        const int c = (j & 7) ^ (r & 7);
        gA[ld] = A + (size_t)(m0 + r) * K + c * 8;
        gB[ld] = W + (size_t)(n0 + r) * K + c * 8;
    }

    f32x4 acc[4][4];
    #pragma unroll
    for (int i = 0; i < 4; ++i)
        #pragma unroll
        for (int j = 0; j < 4; ++j)
            acc[i][j] = (f32x4){0.f, 0.f, 0.f, 0.f};

    const int rA = (wave & 1) * 64 + (lane & 15);
    const int rB = (wave >> 1) * 64 + (lane & 15);
    const int xorL = lane & 7;   // (rA&7) == (rB&7) == lane&7

    for (int k0 = 0; k0 < K; k0 += 64) {
        #pragma unroll
        for (int ld = 0; ld < 4; ++ld)
            __builtin_amdgcn_global_load_lds(
                (const __attribute__((address_space(1))) void*)(gA[ld] + k0),
                (__attribute__((address_space(3))) void*)(sAc + ld * 4096 + wave * 1024), 16, 0, 0);
        #pragma unroll
        for (int ld = 0; ld < 4; ++ld)
            __builtin_amdgcn_global_load_lds(
                (const __attribute__((address_space(1))) void*)(gB[ld] + k0),
                (__attribute__((address_space(3))) void*)(sBc + ld * 4096 + wave * 1024), 16, 0, 0);
        __syncthreads();
        #pragma unroll
        for (int kk = 0; kk < 2; ++kk) {
            const int coff = ((kk * 4 + quad) ^ xorL) * 16;
            f16x8 aF[4], bF[4];
            #pragma unroll
            for (int mi = 0; mi < 4; ++mi)
                aF[mi] = *(const f16x8*)(sAc + (rA + mi * 16) * 128 + coff);
            #pragma unroll
            for (int ni = 0; ni < 4; ++ni)
                bF[ni] = *(const f16x8*)(sBc + (rB + ni * 16) * 128 + coff);
            #pragma unroll
            for (int mi = 0; mi < 4; ++mi)
                #pragma unroll
                for (int ni = 0; ni < 4; ++ni)
                    acc[mi][ni] = __builtin_amdgcn_mfma_f32_16x16x32_f16(aF[mi], bF[ni], acc[mi][ni], 0, 0, 0);
        }
        __syncthreads();
    }

    // epilogue: C/D layout col=lane&15, row=quad*4+reg
    const int colC = lane & 15;
    #pragma unroll
    for (int ni = 0; ni < 4; ++ni) {
        const int n = n0 + (wave >> 1) * 64 + ni * 16 + colC;
        const float bv = bias[n];
        #pragma unroll
        for (int mi = 0; mi < 4; ++mi) {
            const int mb = m0 + (wave & 1) * 64 + mi * 16 + quad * 4;
            #pragma unroll
            for (int r = 0; r < 4; ++r) {
                float v = acc[mi][ni][r] + bv;
                C[(size_t)(mb + r) * N + n] = (_Float16)gelu_f(v);
            }
        }
    }
}

// ---- Kernel 5: output head, clip ----
__global__ __launch_bounds__(256) void out_kernel(
    const _Float16* __restrict__ h2f, const _Float16* __restrict__ h2b,
    const float* __restrict__ Wof, const float* __restrict__ Wob,
    const float* __restrict__ bof, const float* __restrict__ bob,
    float* __restrict__ out)
{
    const int t = blockIdx.x;
    const int z = blockIdx.y;
    const _Float16* __restrict__ h2 = z ? h2b : h2f;
    const float* __restrict__ Wo = z ? Wob : Wof;
    const float bo = z ? bob[0] : bof[0];
    const int tid = threadIdx.x;
    const int c = tid * 8;
    const f16x8 hv = *(const f16x8*)(h2 + (size_t)t * H_DIM + c);
    float acc = 0.f;
    #pragma unroll
    for (int j = 0; j < 8; ++j)
        acc += (float)hv[j] * Wo[c + j];
    #pragma unroll
    for (int off = 32; off >= 1; off >>= 1)
        acc += __shfl_xor(acc, off, 64);
    __shared__ float red[4];
    const int lane = tid & 63, wave = tid >> 6;
    if (lane == 0) red[wave] = acc;
    __syncthreads();
    if (tid == 0) {
        float v = red[0] + red[1] + red[2] + red[3] + bo;
        v = fminf(fmaxf(v, 1e-4f), 1.0f - 1e-4f);
        out[(size_t)z * T_DIM + t] = v;
    }
}

extern "C" void kernel_launch(void* const* d_in, const int* in_sizes, int n_in,
                              void* d_out, int out_size, void* d_ws, size_t ws_size,
                              hipStream_t stream)
{
    (void)in_sizes; (void)n_in; (void)out_size; (void)ws_size;
    const float* mol = (const float*)d_in[0];
    const float* sol = (const float*)d_in[1];
    const float* desc = (const float*)d_in[2];
    const float* rf  = (const float*)d_in[3];
    const float* sv  = (const float*)d_in[4];
    const float* Wf0 = (const float*)d_in[5];
    const float* Wf1 = (const float*)d_in[6];
    const float* Wf2 = (const float*)d_in[7];
    const float* Wof = (const float*)d_in[8];
    const float* Wb0 = (const float*)d_in[9];
    const float* Wb1 = (const float*)d_in[10];
    const float* Wb2 = (const float*)d_in[11];
    const float* Wob = (const float*)d_in[12];
    const float* bf0 = (const float*)d_in[13];
    const float* bf1 = (const float*)d_in[14];
    const float* bf2 = (const float*)d_in[15];
    const float* bof = (const float*)d_in[16];
    const float* bb0 = (const float*)d_in[17];
    const float* bb1 = (const float*)d_in[18];
    const float* bb2 = (const float*)d_in[19];
    const float* bob = (const float*)d_in[20];
    float* out = (float*)d_out;

    char* ws = (char*)d_ws;
    float* fold_f = (float*)(ws + 0);          // 13*2048*4 = 106496 B
    float* fold_b = (float*)(ws + 131072);
    _Float16* Wc = (_Float16*)(ws + 262144);   // 4 x 2048*2048 fp16 = 33554432 B
    const size_t WSZ = (size_t)H_DIM * H_DIM;
    _Float16* W1f_c = Wc;
    _Float16* W2f_c = Wc + WSZ;
    _Float16* W1b_c = Wc + 2 * WSZ;
    _Float16* W2b_c = Wc + 3 * WSZ;
    const size_t HSZ = (size_t)T_DIM * H_DIM;  // 8388608 elems, 16777216 B fp16
    _Float16* h0f = (_Float16*)(ws + 33816576);
    _Float16* h0b = h0f + HSZ;
    _Float16* h1f = (_Float16*)(ws + 33816576 + 2 * 16777216);
    _Float16* h1b = h1f + HSZ;
    _Float16* h2f = h0f;  // reuse: h0 dead after layer 1
    _Float16* h2b = h0b;
    // total ws use: 33816576 + 4*16777216 = 100,925,440 B

    fold_kernel<<<dim3(H_DIM, 2), 256, 0, stream>>>(Wf0, Wb0, bf0, bb0, mol, sv, fold_f, fold_b);
    conv_kernel<<<dim3(H_DIM * H_DIM / 1024, 4), 256, 0, stream>>>(Wf1, Wf2, Wb1, Wb2, Wc);
    h0_kernel<<<dim3(8, 64, 2), 256, 0, stream>>>(fold_f, fold_b, desc, sol, rf, h0f, h0b);
    gemm_kernel<<<dim3(1024), 256, 0, stream>>>(h0f, h0b, W1f_c, W1b_c, bf1, bb1, h1f, h1b);
    gemm_kernel<<<dim3(1024), 256, 0, stream>>>(h1f, h1b, W2f_c, W2b_c, bf2, bb2, h2f, h2b);
    out_kernel<<<dim3(T_DIM, 2), 256, 0, stream>>>(h2f, h2b, Wof, Wob, bof, bob, out);
}

// Round 4
// 488.067 us; speedup vs baseline: 1.1706x; 1.0319x over previous
//
#include <hip/hip_runtime.h>
#include <hip/hip_fp16.h>
#include <math.h>

#define T_DIM 4096
#define MOL_N 2048
#define DESC_N 6
#define NSOL_N 5
#define H_DIM 2048
#define DBLK 2054
#define D_IN_N 12325

typedef _Float16 f16x8 __attribute__((ext_vector_type(8)));
typedef float f32x4 __attribute__((ext_vector_type(4)));

// tanh-form GELU as x * sigmoid(1.5957691x + 0.0713548x^3).
// Max abs deviation from exact erf-GELU ~2e-4 (margin ~1.4e-2).
__device__ __forceinline__ float gelu_f(float x) {
    float v = x * (1.5957691f + 0.0713548f * x * x);
    float e = __expf(-v);
    return x / (1.0f + e);
}

// ---- Kernel 1: fold layer-0 weights against the static input structure ----
// fold layout (floats, per trunk): [0,H)=c0(+bias), [(1+s)H,..)=u_s (s<5),
// [(6+j)H,..)=wd_j (j<6), [12H,13H)=wprev
// Fully unrolled c-loop: 48 independent global loads in flight per wave
// (latency-limited otherwise: only 6 loads/iter).
__global__ __launch_bounds__(256) void fold_kernel(
    const float* __restrict__ W0f, const float* __restrict__ W0b,
    const float* __restrict__ b0f, const float* __restrict__ b0b,
    const float* __restrict__ mol, const float* __restrict__ sv,
    float* __restrict__ fold_f, float* __restrict__ fold_b)
{
    const int h = blockIdx.x;
    const int z = blockIdx.y;
    const float* __restrict__ W0 = z ? W0b : W0f;
    const float* __restrict__ b0 = z ? b0b : b0f;
    float* __restrict__ fold = z ? fold_b : fold_f;
    const float* __restrict__ row = W0 + (size_t)h * D_IN_N;
    const int tid = threadIdx.x;

    float acc[6] = {0.f, 0.f, 0.f, 0.f, 0.f, 0.f};
    #pragma unroll
    for (int i = 0; i < 8; ++i) {
        const int c = tid + i * 256;
        const float m = mol[c];
        acc[0] += row[c] * m;
        #pragma unroll
        for (int s = 0; s < NSOL_N; ++s)
            acc[1 + s] += row[DBLK * (s + 1) + c] * sv[s * MOL_N + c];
    }
    #pragma unroll
    for (int i = 0; i < 6; ++i) {
        float v = acc[i];
        #pragma unroll
        for (int off = 32; off >= 1; off >>= 1)
            v += __shfl_xor(v, off, 64);
        acc[i] = v;
    }
    __shared__ float red[4][6];
    const int lane = tid & 63, wave = tid >> 6;
    if (lane == 0) {
        #pragma unroll
        for (int i = 0; i < 6; ++i) red[wave][i] = acc[i];
    }
    __syncthreads();
    if (tid < 6) {
        float s = red[0][tid] + red[1][tid] + red[2][tid] + red[3][tid];
        if (tid == 0) fold[h] = s + b0[h];
        else fold[(size_t)tid * H_DIM + h] = s;   // u_s at (1+s)H with s=tid-1
    }
    if (tid >= 64 && tid < 70) {
        int j = tid - 64;
        float w = row[MOL_N + j];
        #pragma unroll
        for (int s = 0; s < NSOL_N; ++s) w += row[DBLK * (s + 1) + MOL_N + j];
        fold[(size_t)(6 + j) * H_DIM + h] = w;
    }
    if (tid == 70) fold[(size_t)12 * H_DIM + h] = row[D_IN_N - 1];
}

// ---- Kernel 2: convert W1/W2 (both trunks) fp32 -> fp16 ----
__global__ __launch_bounds__(256) void conv_kernel(
    const float* __restrict__ W1f, const float* __restrict__ W2f,
    const float* __restrict__ W1b, const float* __restrict__ W2b,
    _Float16* __restrict__ dstbase)
{
    const int z = blockIdx.y;
    const float* __restrict__ src = (z == 0) ? W1f : (z == 1) ? W2f : (z == 2) ? W1b : W2b;
    _Float16* __restrict__ dst = dstbase + (size_t)z * H_DIM * H_DIM;
    const int idx = blockIdx.x * 256 + threadIdx.x;
    float4 v = ((const float4*)src)[idx];
    struct h4 { _Float16 a, b, c, d; };
    h4 o;
    o.a = (_Float16)v.x; o.b = (_Float16)v.y; o.c = (_Float16)v.z; o.d = (_Float16)v.w;
    ((h4*)dst)[idx] = o;
}

// ---- Kernel 3: h0 = gelu(folded layer-0), store fp16 ----
__global__ __launch_bounds__(256) void h0_kernel(
    const float* __restrict__ fold_f, const float* __restrict__ fold_b,
    const float* __restrict__ desc, const float* __restrict__ sol,
    const float* __restrict__ rf,
    _Float16* __restrict__ h0f, _Float16* __restrict__ h0b)
{
    const int z = blockIdx.z;
    const float* __restrict__ fold = z ? fold_b : fold_f;
    _Float16* __restrict__ h0 = z ? h0b : h0f;
    const int h = blockIdx.x * 256 + threadIdx.x;
    const int tbase = blockIdx.y * 64;

    const float c0 = fold[h];
    float u[NSOL_N], wd[DESC_N];
    #pragma unroll
    for (int s = 0; s < NSOL_N; ++s) u[s] = fold[(size_t)(1 + s) * H_DIM + h];
    #pragma unroll
    for (int j = 0; j < DESC_N; ++j) wd[j] = fold[(size_t)(6 + j) * H_DIM + h];
    const float wp = fold[(size_t)12 * H_DIM + h];

    for (int i = 0; i < 64; ++i) {
        const int t = tbase + i;
        float pv;
        if (z == 0) pv = (t == 0) ? 0.5f : rf[t - 1];
        else        pv = (t == T_DIM - 1) ? 0.5f : rf[t + 1];
        float pre = c0 + wp * pv;
        #pragma unroll
        for (int s = 0; s < NSOL_N; ++s) pre += u[s] * sol[t * NSOL_N + s];
        #pragma unroll
        for (int j = 0; j < DESC_N; ++j) pre += wd[j] * desc[t * DESC_N + j];
        h0[(size_t)t * H_DIM + h] = (_Float16)gelu_f(pre);
    }
}

// ---- Kernel 4: batched GEMM  C[m,n] = gelu(sum_k A[m,k]*W[n,k] + bias[n]) ----
// 128x128 tile, BK=64, global_load_lds w16, 3-bit XOR k-chunk swizzle
// (0 SQ_LDS_BANK_CONFLICT verified). XCD-aware tile map (FETCH near
// compulsory, verified r3).
__global__ __launch_bounds__(256) void gemm_kernel(
    const _Float16* __restrict__ Af, const _Float16* __restrict__ Ab,
    const _Float16* __restrict__ Wfp, const _Float16* __restrict__ Wbp,
    const float* __restrict__ bfp, const float* __restrict__ bbp,
    _Float16* __restrict__ Cf, _Float16* __restrict__ Cb)
{
    constexpr int K = H_DIM;
    constexpr int N = H_DIM;
    const int bid = blockIdx.x;
    const int xcd = bid & 7;
    const int slot = bid >> 3;
    const int z = xcd & 1;
    const int q = xcd >> 1;
    const int m0 = (q * 8 + (slot & 7)) * 128;
    const int n0 = (slot >> 3) * 128;

    const _Float16* __restrict__ A = z ? Ab : Af;
    const _Float16* __restrict__ W = z ? Wbp : Wfp;
    const float* __restrict__ bias = z ? bbp : bfp;
    _Float16* __restrict__ C = z ? Cb : Cf;

    __shared__ _Float16 sA[128 * 64];
    __shared__ _Float16 sB[128 * 64];

    const int tid = threadIdx.x;
    const int wave = tid >> 6;
    const int lane = tid & 63;
    const int quad = lane >> 4;

    char* sAc = (char*)sA;
    char* sBc = (char*)sB;

    const _Float16* gA[4];
    const _Float16* gB[4];
    #pragma unroll
    for (int ld = 0; ld < 4; ++ld) {
        const int j = ld * 256 + tid;
        const int r = j >> 3;
        const int c = (j & 7) ^ (r & 7);
        gA[ld] = A + (size_t)(m0 + r) * K + c * 8;
        gB[ld] = W + (size_t)(n0 + r) * K + c * 8;
    }

    f32x4 acc[4][4];
    #pragma unroll
    for (int i = 0; i < 4; ++i)
        #pragma unroll
        for (int j = 0; j < 4; ++j)
            acc[i][j] = (f32x4){0.f, 0.f, 0.f, 0.f};

    const int rA = (wave & 1) * 64 + (lane & 15);
    const int rB = (wave >> 1) * 64 + (lane & 15);
    const int xorL = lane & 7;

    for (int k0 = 0; k0 < K; k0 += 64) {
        #pragma unroll
        for (int ld = 0; ld < 4; ++ld)
            __builtin_amdgcn_global_load_lds(
                (const __attribute__((address_space(1))) void*)(gA[ld] + k0),
                (__attribute__((address_space(3))) void*)(sAc + ld * 4096 + wave * 1024), 16, 0, 0);
        #pragma unroll
        for (int ld = 0; ld < 4; ++ld)
            __builtin_amdgcn_global_load_lds(
                (const __attribute__((address_space(1))) void*)(gB[ld] + k0),
                (__attribute__((address_space(3))) void*)(sBc + ld * 4096 + wave * 1024), 16, 0, 0);
        __syncthreads();
        #pragma unroll
        for (int kk = 0; kk < 2; ++kk) {
            const int coff = ((kk * 4 + quad) ^ xorL) * 16;
            f16x8 aF[4], bF[4];
            #pragma unroll
            for (int mi = 0; mi < 4; ++mi)
                aF[mi] = *(const f16x8*)(sAc + (rA + mi * 16) * 128 + coff);
            #pragma unroll
            for (int ni = 0; ni < 4; ++ni)
                bF[ni] = *(const f16x8*)(sBc + (rB + ni * 16) * 128 + coff);
            #pragma unroll
            for (int mi = 0; mi < 4; ++mi)
                #pragma unroll
                for (int ni = 0; ni < 4; ++ni)
                    acc[mi][ni] = __builtin_amdgcn_mfma_f32_16x16x32_f16(aF[mi], bF[ni], acc[mi][ni], 0, 0, 0);
        }
        __syncthreads();
    }

    const int colC = lane & 15;
    #pragma unroll
    for (int ni = 0; ni < 4; ++ni) {
        const int n = n0 + (wave >> 1) * 64 + ni * 16 + colC;
        const float bv = bias[n];
        #pragma unroll
        for (int mi = 0; mi < 4; ++mi) {
            const int mb = m0 + (wave & 1) * 64 + mi * 16 + quad * 4;
            #pragma unroll
            for (int r = 0; r < 4; ++r) {
                float v = acc[mi][ni][r] + bv;
                C[(size_t)(mb + r) * N + n] = (_Float16)gelu_f(v);
            }
        }
    }
}

// ---- Kernel 4b: GEMM layer-2 with FUSED output head ----
// Same K-loop as gemm_kernel; epilogue computes gelu(pre) in fp32, dots with
// Wo over this block's 128 n-cols, shuffle-reduces across the 16 colC lanes,
// and atomicAdds fp32 row partials into out_acc[z*T + row].
__global__ __launch_bounds__(256) void gemm_out_kernel(
    const _Float16* __restrict__ Af, const _Float16* __restrict__ Ab,
    const _Float16* __restrict__ Wfp, const _Float16* __restrict__ Wbp,
    const float* __restrict__ bfp, const float* __restrict__ bbp,
    const float* __restrict__ Wof, const float* __restrict__ Wob,
    float* __restrict__ out_acc)
{
    constexpr int K = H_DIM;
    const int bid = blockIdx.x;
    const int xcd = bid & 7;
    const int slot = bid >> 3;
    const int z = xcd & 1;
    const int q = xcd >> 1;
    const int m0 = (q * 8 + (slot & 7)) * 128;
    const int n0 = (slot >> 3) * 128;

    const _Float16* __restrict__ A = z ? Ab : Af;
    const _Float16* __restrict__ W = z ? Wbp : Wfp;
    const float* __restrict__ bias = z ? bbp : bfp;
    const float* __restrict__ Wo = z ? Wob : Wof;

    __shared__ _Float16 sA[128 * 64];
    __shared__ _Float16 sB[128 * 64];

    const int tid = threadIdx.x;
    const int wave = tid >> 6;
    const int lane = tid & 63;
    const int quad = lane >> 4;

    char* sAc = (char*)sA;
    char* sBc = (char*)sB;

    const _Float16* gA[4];
    const _Float16* gB[4];
    #pragma unroll
    for (int ld = 0; ld < 4; ++ld) {
        const int j = ld * 256 + tid;
        const int r = j >> 3;
        const int c = (j & 7) ^ (r & 7);
        gA[ld] = A + (size_t)(m0 + r) * K + c * 8;
        gB[ld] = W + (size_t)(n0 + r) * K + c * 8;
    }

    f32x4 acc[4][4];
    #pragma unroll
    for (int i = 0; i < 4; ++i)
        #pragma unroll
        for (int j = 0; j < 4; ++j)
            acc[i][j] = (f32x4){0.f, 0.f, 0.f, 0.f};

    const int rA = (wave & 1) * 64 + (lane & 15);
    const int rB = (wave >> 1) * 64 + (lane & 15);
    const int xorL = lane & 7;

    for (int k0 = 0; k0 < K; k0 += 64) {
        #pragma unroll
        for (int ld = 0; ld < 4; ++ld)
            __builtin_amdgcn_global_load_lds(
                (const __attribute__((address_space(1))) void*)(gA[ld] + k0),
                (__attribute__((address_space(3))) void*)(sAc + ld * 4096 + wave * 1024), 16, 0, 0);
        #pragma unroll
        for (int ld = 0; ld < 4; ++ld)
            __builtin_amdgcn_global_load_lds(
                (const __attribute__((address_space(1))) void*)(gB[ld] + k0),
                (__attribute__((address_space(3))) void*)(sBc + ld * 4096 + wave * 1024), 16, 0, 0);
        __syncthreads();
        #pragma unroll
        for (int kk = 0; kk < 2; ++kk) {
            const int coff = ((kk * 4 + quad) ^ xorL) * 16;
            f16x8 aF[4], bF[4];
            #pragma unroll
            for (int mi = 0; mi < 4; ++mi)
                aF[mi] = *(const f16x8*)(sAc + (rA + mi * 16) * 128 + coff);
            #pragma unroll
            for (int ni = 0; ni < 4; ++ni)
                bF[ni] = *(const f16x8*)(sBc + (rB + ni * 16) * 128 + coff);
            #pragma unroll
            for (int mi = 0; mi < 4; ++mi)
                #pragma unroll
                for (int ni = 0; ni < 4; ++ni)
                    acc[mi][ni] = __builtin_amdgcn_mfma_f32_16x16x32_f16(aF[mi], bF[ni], acc[mi][ni], 0, 0, 0);
        }
        __syncthreads();
    }

    // fused head epilogue
    const int colC = lane & 15;
    float bv[4], wo[4];
    #pragma unroll
    for (int ni = 0; ni < 4; ++ni) {
        const int n = n0 + (wave >> 1) * 64 + ni * 16 + colC;
        bv[ni] = bias[n];
        wo[ni] = Wo[n];
    }
    #pragma unroll
    for (int mi = 0; mi < 4; ++mi) {
        #pragma unroll
        for (int r = 0; r < 4; ++r) {
            float s = 0.f;
            #pragma unroll
            for (int ni = 0; ni < 4; ++ni)
                s += gelu_f(acc[mi][ni][r] + bv[ni]) * wo[ni];
            // reduce across the 16 colC lanes (lane bits 0..3)
            s += __shfl_xor(s, 1, 64);
            s += __shfl_xor(s, 2, 64);
            s += __shfl_xor(s, 4, 64);
            s += __shfl_xor(s, 8, 64);
            if (colC == 0) {
                const int row = m0 + (wave & 1) * 64 + mi * 16 + quad * 4 + r;
                atomicAdd(&out_acc[z * T_DIM + row], s);
            }
        }
    }
}

// ---- Kernel 5: finalize — bias + clip ----
__global__ __launch_bounds__(256) void finalize_kernel(
    const float* __restrict__ out_acc,
    const float* __restrict__ bof, const float* __restrict__ bob,
    float* __restrict__ out)
{
    const int idx = blockIdx.x * 256 + threadIdx.x;
    const int z = idx >> 12;
    float v = out_acc[idx] + (z ? bob[0] : bof[0]);
    v = fminf(fmaxf(v, 1e-4f), 1.0f - 1e-4f);
    out[idx] = v;
}

extern "C" void kernel_launch(void* const* d_in, const int* in_sizes, int n_in,
                              void* d_out, int out_size, void* d_ws, size_t ws_size,
                              hipStream_t stream)
{
    (void)in_sizes; (void)n_in; (void)out_size; (void)ws_size;
    const float* mol = (const float*)d_in[0];
    const float* sol = (const float*)d_in[1];
    const float* desc = (const float*)d_in[2];
    const float* rf  = (const float*)d_in[3];
    const float* sv  = (const float*)d_in[4];
    const float* Wf0 = (const float*)d_in[5];
    const float* Wf1 = (const float*)d_in[6];
    const float* Wf2 = (const float*)d_in[7];
    const float* Wof = (const float*)d_in[8];
    const float* Wb0 = (const float*)d_in[9];
    const float* Wb1 = (const float*)d_in[10];
    const float* Wb2 = (const float*)d_in[11];
    const float* Wob = (const float*)d_in[12];
    const float* bf0 = (const float*)d_in[13];
    const float* bf1 = (const float*)d_in[14];
    const float* bf2 = (const float*)d_in[15];
    const float* bof = (const float*)d_in[16];
    const float* bb0 = (const float*)d_in[17];
    const float* bb1 = (const float*)d_in[18];
    const float* bb2 = (const float*)d_in[19];
    const float* bob = (const float*)d_in[20];
    float* out = (float*)d_out;

    char* ws = (char*)d_ws;
    float* fold_f = (float*)(ws + 0);          // 13*2048*4 = 106496 B
    float* fold_b = (float*)(ws + 131072);
    _Float16* Wc = (_Float16*)(ws + 262144);   // 4 x 2048*2048 fp16 = 33554432 B
    const size_t WSZ = (size_t)H_DIM * H_DIM;
    _Float16* W1f_c = Wc;
    _Float16* W2f_c = Wc + WSZ;
    _Float16* W1b_c = Wc + 2 * WSZ;
    _Float16* W2b_c = Wc + 3 * WSZ;
    const size_t HSZ = (size_t)T_DIM * H_DIM;  // 16777216 B fp16 each
    _Float16* h0f = (_Float16*)(ws + 33816576);
    _Float16* h0b = h0f + HSZ;
    _Float16* h1f = (_Float16*)(ws + 33816576 + 2 * 16777216);
    _Float16* h1b = h1f + HSZ;
    float* out_acc = (float*)(ws + 33816576);  // reuse h0f region (dead after gemm1); 32 KB
    // total ws use: 33816576 + 4*16777216 = 100,925,440 B

    fold_kernel<<<dim3(H_DIM, 2), 256, 0, stream>>>(Wf0, Wb0, bf0, bb0, mol, sv, fold_f, fold_b);
    conv_kernel<<<dim3(H_DIM * H_DIM / 1024, 4), 256, 0, stream>>>(Wf1, Wf2, Wb1, Wb2, Wc);
    h0_kernel<<<dim3(8, 64, 2), 256, 0, stream>>>(fold_f, fold_b, desc, sol, rf, h0f, h0b);
    gemm_kernel<<<dim3(1024), 256, 0, stream>>>(h0f, h0b, W1f_c, W1b_c, bf1, bb1, h1f, h1b);
    hipMemsetAsync(out_acc, 0, 2 * T_DIM * sizeof(float), stream);
    gemm_out_kernel<<<dim3(1024), 256, 0, stream>>>(h1f, h1b, W2f_c, W2b_c, bf2, bb2, Wof, Wob, out_acc);
    finalize_kernel<<<dim3(2 * T_DIM / 256), 256, 0, stream>>>(out_acc, bof, bob, out);
}